// Round 10
// baseline (110.576 us; speedup 1.0000x reference)
//
#include <hip/hip_runtime.h>
#include <hip/hip_bf16.h>

#define NB 16
#define NT 2048
#define NDM 1024
#define NDK 128

typedef __bf16 bf16;
typedef bf16 bf16x4 __attribute__((ext_vector_type(4)));
typedef bf16 bf16x8 __attribute__((ext_vector_type(8)));
typedef float f32x4 __attribute__((ext_vector_type(4)));

__device__ inline bf16 to_bf16(float f) {
    __hip_bfloat16 h = __float2bfloat16(f);
    return *reinterpret_cast<bf16*>(&h);
}

// async 16B global -> LDS (dest: wave-uniform base, HW adds lane*16; src per-lane)
__device__ inline void gload_lds16(const void* g, void* l) {
    __builtin_amdgcn_global_load_lds(
        (const __attribute__((address_space(1))) unsigned int*)g,
        (__attribute__((address_space(3))) unsigned int*)l, 16, 0, 0);
}

// ---------------------------------------------------------------------------
// Kernel 1: W [1024][128] f32  ->  Wt bf16 [3][128][1024]  (transposed, K-major)
// ---------------------------------------------------------------------------
__global__ __launch_bounds__(256) void transpose_w_kernel(
        const float* __restrict__ Wq, const float* __restrict__ Wk,
        const float* __restrict__ Wv, bf16* __restrict__ Wt) {
    int idx = blockIdx.x * 256 + threadIdx.x;
    int w = idx >> 17;
    int r = idx & (NDM * NDK - 1);
    int k = r >> 7;
    int n = r & (NDK - 1);
    const float* W = (w == 0) ? Wq : ((w == 1) ? Wk : Wv);
    Wt[(size_t)w * NDK * NDM + (size_t)n * NDM + k] = to_bf16(W[(size_t)k * NDK + n]);
}

// ---------------------------------------------------------------------------
// Kernel 2: FUSED QKV projection, fat-phase: BK=128, only 8 K-steps.
// 96 MFMA per wave per barrier-pair (4x the old 24) so the per-phase stall
// amortizes (R8 counters: 32 thin phases were stall-dominated).
// A [128][128]bf16: reg-staged (f32 global->regs->cvt->ds_write; next-tile
// loads issued after the drain barrier = fly under compute). B = all 3 planes
// [384][128]bf16 via global_load_lds, pre-swizzled per-lane source.
// Both tiles XOR-swizzled: 16B-chunk ^= row&7 (<=2-way, free).
// Epilogue: Q,K direct; V restaged in LDS -> Vt [B][128][T] coalesced.
// ---------------------------------------------------------------------------
__global__ __launch_bounds__(512, 2) void proj_fused_kernel(
        const float* __restrict__ x, const bf16* __restrict__ Wt,
        bf16* __restrict__ qkv, bf16* __restrict__ Vt) {
    __shared__ __align__(16) char smem[131072];  // A 32KB @0 | B 96KB @32768
    const int tid = threadIdx.x;
    const int lane = tid & 63, wave = tid >> 6;
    const int wr = wave >> 2, wc = wave & 3;     // 2 x 4 wave grid
    const int r16 = lane & 15, kg = lane >> 4;
    const int mb = blockIdx.x;
    const float* xA = x + (size_t)mb * 128 * NDM;

    bf16* As = (bf16*)smem;                 // [128][128] elem-indexed, swizzled
    bf16* Bs = (bf16*)(smem + 32768);       // [384][128] swizzled

    // A staging: thread -> row a_r (0..127), 32 consecutive cols at a_cb
    const int a_r = tid >> 2;
    const int a_cb = (tid & 3) * 32;

    float4 areg[8];
    auto loadA = [&](int kt) {
        const float* src = xA + (size_t)a_r * NDM + kt * 128 + a_cb;
#pragma unroll
        for (int i = 0; i < 8; i++)
            areg[i] = *reinterpret_cast<const float4*>(src + i * 4);
    };
    auto writeA = [&]() {
#pragma unroll
        for (int i = 0; i < 4; i++) {
            int ch = (a_cb >> 3) + i;            // 16B chunk 0..15
            int chs = ch ^ (a_r & 7);
            const float4 lo = areg[2 * i], hi = areg[2 * i + 1];
            bf16x8 v;
            v[0] = to_bf16(lo.x); v[1] = to_bf16(lo.y); v[2] = to_bf16(lo.z); v[3] = to_bf16(lo.w);
            v[4] = to_bf16(hi.x); v[5] = to_bf16(hi.y); v[6] = to_bf16(hi.z); v[7] = to_bf16(hi.w);
            *reinterpret_cast<bf16x8*>(As + a_r * 128 + chs * 8) = v;
        }
    };
    auto stageB = [&](int kt) {
#pragma unroll
        for (int p = 0; p < 12; p++) {
            int D = (p * 8 + wave) * 64 + lane;   // chunk id 0..6143
            int brow = D >> 4, bch = D & 15;
            int sch = bch ^ (brow & 7);           // inverse-swizzled source
            gload_lds16(Wt + (size_t)(brow >> 7) * (NDK * NDM)
                           + (size_t)(brow & 127) * NDM + kt * 128 + sch * 8,
                        Bs + (size_t)(p * 8 + wave) * 512);
        }
    };

    f32x4 acc[4][6];
#pragma unroll
    for (int m = 0; m < 4; m++)
#pragma unroll
        for (int n = 0; n < 6; n++) acc[m][n] = (f32x4){0.f, 0.f, 0.f, 0.f};

    loadA(0);
    for (int kt = 0; kt < 8; kt++) {
        __syncthreads();               // all waves done reading LDS; A regs arrived
        writeA();
        stageB(kt);
        __syncthreads();               // drain ds_writes + B gloads
        if (kt + 1 < 8) loadA(kt + 1); // flies during compute, drained @ next bar

#pragma unroll
        for (int kk = 0; kk < 4; kk++) {
            bf16x8 af[4], bfr[6];
#pragma unroll
            for (int m = 0; m < 4; m++) {
                int arow = wr * 64 + m * 16 + r16;
                int ch = (kk * 4 + kg) ^ (arow & 7);
                af[m] = *reinterpret_cast<const bf16x8*>(As + arow * 128 + ch * 8);
            }
#pragma unroll
            for (int nf = 0; nf < 6; nf++) {
                int brow = wc * 96 + nf * 16 + r16;
                int ch = (kk * 4 + kg) ^ (brow & 7);
                bfr[nf] = *reinterpret_cast<const bf16x8*>(Bs + brow * 128 + ch * 8);
            }
#pragma unroll
            for (int m = 0; m < 4; m++)
#pragma unroll
                for (int nf = 0; nf < 6; nf++)
                    acc[m][nf] = __builtin_amdgcn_mfma_f32_16x16x32_bf16(af[m], bfr[nf], acc[m][nf], 0, 0, 0);
        }
    }

    // ---- epilogue ----
    __syncthreads();   // LDS free; reuse as Tl
    bf16 (*Tl)[136] = reinterpret_cast<bf16(*)[136]>(smem);
#pragma unroll
    for (int m = 0; m < 4; m++) {
        int rowb = mb * 128 + wr * 64 + m * 16 + kg * 4;
        int tl = wr * 64 + m * 16 + kg * 4;
#pragma unroll
        for (int nf = 0; nf < 6; nf++) {
            int col = wc * 96 + nf * 16 + r16;
            int w = col >> 7, ncol = col & 127;
            if (w < 2) {
                bf16* outw = qkv + (size_t)w * (size_t)(NB * NT) * NDK;
#pragma unroll
                for (int r = 0; r < 4; r++)
                    outw[(size_t)(rowb + r) * NDK + ncol] = to_bf16(acc[m][nf][r]);
            } else {
                bf16x4 pv = { to_bf16(acc[m][nf][0]), to_bf16(acc[m][nf][1]),
                              to_bf16(acc[m][nf][2]), to_bf16(acc[m][nf][3]) };
                *reinterpret_cast<bf16x4*>(&Tl[ncol][tl]) = pv;
            }
        }
    }
    __syncthreads();
    const int b = mb >> 4;
    const int t0 = (mb & 15) * 128;
    bf16* Vb = Vt + (size_t)b * NDK * NT;
#pragma unroll
    for (int p = 0; p < 4; p++) {
        int idx = p * 512 + tid;          // 2048 chunks: 128 d-rows x 16
        int d = idx >> 4, c = idx & 15;
        *reinterpret_cast<bf16x8*>(&Vb[(size_t)d * NT + t0 + c * 8]) =
            *reinterpret_cast<const bf16x8*>(&Tl[d][c * 8]);
    }
}

// ---------------------------------------------------------------------------
// Kernel 3: causal flash attention (unchanged: swapped-QK^T softmax, dbuf K/V
// LDS, 1 barrier/step, reg-prefetch, XCD-pinned batches).
// ---------------------------------------------------------------------------
__global__ __launch_bounds__(256) void attn_kernel(
        const bf16* __restrict__ Q, const bf16* __restrict__ K,
        const bf16* __restrict__ Vt, float* __restrict__ out) {
    __shared__ bf16 Ks[2][64][128];
    __shared__ bf16 Vs[2][128][64];
    __shared__ bf16 Ps[4][16][72];
    const int tid = threadIdx.x, lane = tid & 63, wave = tid >> 6;
    const int r16 = lane & 15, kg = lane >> 4;

    const int bid = blockIdx.x;
    const int xcd = bid & 7;
    const int j = bid >> 3;
    const int b = xcd * 2 + (j & 1);
    const int qb = (NT / 64 - 1) - (j >> 1);
    const int q0 = qb * 64;
    const size_t baseB = (size_t)b * NT * NDK;
    const size_t baseVt = (size_t)b * NDK * NT;

    const float scale = 0.08838834764831843f;
    bf16x8 qf[4];
    const int qglob = q0 + wave * 16 + r16;
#pragma unroll
    for (int kc = 0; kc < 4; kc++) {
        bf16x8 raw = *reinterpret_cast<const bf16x8*>(&Q[baseB + (size_t)qglob * NDK + kc * 32 + kg * 8]);
#pragma unroll
        for (int jj = 0; jj < 8; jj++) raw[jj] = to_bf16((float)raw[jj] * scale);
        qf[kc] = raw;
    }

    f32x4 o[8];
#pragma unroll
    for (int n = 0; n < 8; n++) o[n] = (f32x4){0.f, 0.f, 0.f, 0.f};
    float mrun = -INFINITY;
    float lrun = 0.f;

    int krow[4], kcol[4], vrow[4], vcol[4];
#pragma unroll
    for (int i = 0; i < 4; i++) {
        int idx = i * 256 + tid;
        krow[i] = idx >> 4; kcol[i] = idx & 15;
        vrow[i] = idx >> 3; vcol[i] = idx & 7;
    }

    const int nsteps = qb + 1;
    bf16x8 kreg[4], vreg[4];
#pragma unroll
    for (int i = 0; i < 4; i++) {
        kreg[i] = *reinterpret_cast<const bf16x8*>(&K[baseB + (size_t)krow[i] * NDK + kcol[i] * 8]);
        vreg[i] = *reinterpret_cast<const bf16x8*>(&Vt[baseVt + (size_t)vrow[i] * NT + vcol[i] * 8]);
    }
#pragma unroll
    for (int i = 0; i < 4; i++) {
        *reinterpret_cast<bf16x8*>(&Ks[0][krow[i]][(kcol[i] ^ (krow[i] & 7)) * 8]) = kreg[i];
        *reinterpret_cast<bf16x8*>(&Vs[0][vrow[i]][(vcol[i] ^ (vrow[i] & 7)) * 8]) = vreg[i];
    }
    if (nsteps > 1) {
#pragma unroll
        for (int i = 0; i < 4; i++) {
            kreg[i] = *reinterpret_cast<const bf16x8*>(&K[baseB + (size_t)(64 + krow[i]) * NDK + kcol[i] * 8]);
            vreg[i] = *reinterpret_cast<const bf16x8*>(&Vt[baseVt + (size_t)vrow[i] * NT + 64 + vcol[i] * 8]);
        }
    }
    __syncthreads();

    for (int s = 0; s < nsteps; s++) {
        const int cur = s & 1;
        const int kv0 = s * 64;

        f32x4 sfr[4];
#pragma unroll
        for (int n = 0; n < 4; n++) sfr[n] = (f32x4){0.f, 0.f, 0.f, 0.f};
#pragma unroll
        for (int n = 0; n < 4; n++) {
            const int krw = n * 16 + r16;
#pragma unroll
            for (int kc = 0; kc < 4; kc++) {
                bf16x8 kf = *reinterpret_cast<const bf16x8*>(&Ks[cur][krw][((kc * 4 + kg) ^ (krw & 7)) * 8]);
                sfr[n] = __builtin_amdgcn_mfma_f32_16x16x32_bf16(kf, qf[kc], sfr[n], 0, 0, 0);
            }
        }

        if (s == nsteps - 1) {
#pragma unroll
            for (int n = 0; n < 4; n++)
#pragma unroll
                for (int r = 0; r < 4; r++)
                    if (kv0 + n * 16 + kg * 4 + r > qglob) sfr[n][r] = -INFINITY;
        }

        float pm = -INFINITY;
#pragma unroll
        for (int n = 0; n < 4; n++) {
            float t0 = fmaxf(fmaxf(sfr[n][0], sfr[n][1]), fmaxf(sfr[n][2], sfr[n][3]));
            pm = fmaxf(pm, t0);
        }
        pm = fmaxf(pm, __shfl_xor(pm, 16, 64));
        pm = fmaxf(pm, __shfl_xor(pm, 32, 64));

        if (__any(pm > mrun)) {
            float mnew = fmaxf(mrun, pm);
            float corr = __expf(mrun - mnew);
            mrun = mnew;
            lrun *= corr;
            float co[4];
#pragma unroll
            for (int r = 0; r < 4; r++) co[r] = __shfl(corr, kg * 4 + r, 64);
#pragma unroll
            for (int n = 0; n < 8; n++)
#pragma unroll
                for (int r = 0; r < 4; r++) o[n][r] *= co[r];
        }

        float ps = 0.f;
#pragma unroll
        for (int n = 0; n < 4; n++) {
            bf16x4 pw;
#pragma unroll
            for (int r = 0; r < 4; r++) {
                float pv = __expf(sfr[n][r] - mrun);
                ps += pv;
                pw[r] = to_bf16(pv);
            }
            *reinterpret_cast<bf16x4*>(&Ps[wave][r16][n * 16 + kg * 4]) = pw;
        }
        ps += __shfl_xor(ps, 16, 64);
        ps += __shfl_xor(ps, 32, 64);
        lrun += ps;

#pragma unroll
        for (int kc2 = 0; kc2 < 2; kc2++) {
            bf16x8 pf = *reinterpret_cast<const bf16x8*>(&Ps[wave][r16][kc2 * 32 + kg * 8]);
#pragma unroll
            for (int n = 0; n < 8; n++) {
                const int vrw = n * 16 + r16;
                bf16x8 vf = *reinterpret_cast<const bf16x8*>(&Vs[cur][vrw][((kc2 * 4 + kg) ^ (vrw & 7)) * 8]);
                o[n] = __builtin_amdgcn_mfma_f32_16x16x32_bf16(pf, vf, o[n], 0, 0, 0);
            }
        }

        if (s + 1 < nsteps) {
#pragma unroll
            for (int i = 0; i < 4; i++) {
                *reinterpret_cast<bf16x8*>(&Ks[1 - cur][krow[i]][(kcol[i] ^ (krow[i] & 7)) * 8]) = kreg[i];
                *reinterpret_cast<bf16x8*>(&Vs[1 - cur][vrow[i]][(vcol[i] ^ (vrow[i] & 7)) * 8]) = vreg[i];
            }
            if (s + 2 < nsteps) {
                const int kv2 = (s + 2) * 64;
#pragma unroll
                for (int i = 0; i < 4; i++) {
                    kreg[i] = *reinterpret_cast<const bf16x8*>(&K[baseB + (size_t)(kv2 + krow[i]) * NDK + kcol[i] * 8]);
                    vreg[i] = *reinterpret_cast<const bf16x8*>(&Vt[baseVt + (size_t)vrow[i] * NT + kv2 + vcol[i] * 8]);
                }
            }
        }
        __syncthreads();
    }

    float linv = 1.0f / lrun;
    float li[4];
#pragma unroll
    for (int r = 0; r < 4; r++) li[r] = __shfl(linv, kg * 4 + r, 64);
#pragma unroll
    for (int n = 0; n < 8; n++)
#pragma unroll
        for (int r = 0; r < 4; r++) {
            int row = q0 + wave * 16 + kg * 4 + r;
            int col = n * 16 + r16;
            out[baseB + (size_t)row * NDK + col] = o[n][r] * li[r];
        }
}

// ---------------------------------------------------------------------------
extern "C" void kernel_launch(void* const* d_in, const int* in_sizes, int n_in,
                              void* d_out, int out_size, void* d_ws, size_t ws_size,
                              hipStream_t stream) {
    const float* x  = (const float*)d_in[0];
    const float* Wq = (const float*)d_in[1];
    const float* Wk = (const float*)d_in[2];
    const float* Wv = (const float*)d_in[3];
    float* out = (float*)d_out;

    char* ws = (char*)d_ws;
    bf16* Wt  = (bf16*)ws;                        // 768 KB
    bf16* qkv = (bf16*)(ws + (1ull << 20));       // Q,K planes: 16 MB
    bf16* Vtg = (bf16*)(ws + (26ull << 20));      // V^T [B][128][T]: 8 MB

    transpose_w_kernel<<<(3 * NDM * NDK) / 256, 256, 0, stream>>>(Wq, Wk, Wv, Wt);

    // fused QKV projection, fat-phase BK=128 (8 K-steps)
    proj_fused_kernel<<<(NB * NT) / 128, 512, 0, stream>>>(x, Wt, qkv, Vtg);

    bf16* Qp = qkv;
    bf16* Kp = qkv + (size_t)(NB * NT) * NDK;

    attn_kernel<<<dim3((NT / 64) * NB), 256, 0, stream>>>(Qp, Kp, Vtg, out);
}

// Round 11
// 101.475 us; speedup vs baseline: 1.0897x; 1.0897x over previous
//
#include <hip/hip_runtime.h>
#include <hip/hip_bf16.h>

#define NB 16
#define NT 2048
#define NDM 1024
#define NDK 128

typedef __bf16 bf16;
typedef bf16 bf16x4 __attribute__((ext_vector_type(4)));
typedef bf16 bf16x8 __attribute__((ext_vector_type(8)));
typedef float f32x4 __attribute__((ext_vector_type(4)));

__device__ inline bf16 to_bf16(float f) {
    __hip_bfloat16 h = __float2bfloat16(f);
    return *reinterpret_cast<bf16*>(&h);
}

// async 16B global -> LDS (dest: wave-uniform base, HW adds lane*16; src per-lane)
__device__ inline void gload_lds16(const void* g, void* l) {
    __builtin_amdgcn_global_load_lds(
        (const __attribute__((address_space(1))) unsigned int*)g,
        (__attribute__((address_space(3))) unsigned int*)l, 16, 0, 0);
}

#define VMCNT(n) asm volatile("s_waitcnt vmcnt(" #n ")" ::: "memory")
#define LGKM0()  asm volatile("s_waitcnt lgkmcnt(0)" ::: "memory")
#define SCHEDB() __builtin_amdgcn_sched_barrier(0)

// ---------------------------------------------------------------------------
// Kernel 1: W [1024][128] f32  ->  Wt bf16 [3][128][1024]  (transposed, K-major)
// ---------------------------------------------------------------------------
__global__ __launch_bounds__(256) void transpose_w_kernel(
        const float* __restrict__ Wq, const float* __restrict__ Wk,
        const float* __restrict__ Wv, bf16* __restrict__ Wt) {
    int idx = blockIdx.x * 256 + threadIdx.x;
    int w = idx >> 17;
    int r = idx & (NDM * NDK - 1);
    int k = r >> 7;
    int n = r & (NDK - 1);
    const float* W = (w == 0) ? Wq : ((w == 1) ? Wk : Wv);
    Wt[(size_t)w * NDK * NDM + (size_t)n * NDM + k] = to_bf16(W[(size_t)k * NDK + n]);
}

// ---------------------------------------------------------------------------
// Kernel 2: FUSED QKV projection with TRUE counted-vmcnt pipeline (T4).
// BK=32, dbuf LDS 64KB. Per iter: compute(cur) -> vmcnt(3) (A regs) ->
// writeA(nxt) -> lgkmcnt(0) -> raw s_barrier (NO vm drain) -> issue t+2
// stage -> vmcnt(5) (retires B(t+1) only). B gloads fly across barriers.
// ---------------------------------------------------------------------------
__global__ __launch_bounds__(512, 2) void proj_fused_kernel(
        const float* __restrict__ x, const bf16* __restrict__ Wt,
        bf16* __restrict__ qkv, bf16* __restrict__ Vt) {
    // As[2]: 128x32 bf16 (8KB each) @0 | Bs[2]: 384x32 bf16 (24KB each) @16384
    __shared__ __align__(16) char smem[65536];
    const int tid = threadIdx.x;
    const int lane = tid & 63, wave = tid >> 6;
    const int wr = wave >> 2, wc = wave & 3;
    const int r16 = lane & 15, kg = lane >> 4;
    const int mb = blockIdx.x;
    const float* xA = x + (size_t)mb * 128 * NDM;

    auto ASB = [&](int b) -> bf16* { return (bf16*)(smem + b * 8192); };
    auto BSB = [&](int b) -> bf16* { return (bf16*)(smem + 16384 + b * 24576); };

    // A: 512 chunks (128 rows x 4 of 8f32->bf16x8); 1/thread; dest swizzled
    const int a_row = tid >> 2, a_c = tid & 3;
    const int a_dst = (a_row * 4 + (a_c ^ ((a_row >> 1) & 3))) * 8;
    const size_t a_src = (size_t)a_row * NDM + a_c * 8;

    float4 alo, ahi;
    auto loadA = [&](int kt) {    // 2 global vmem loads
        const float* src = xA + a_src + kt * 32;
        alo = *reinterpret_cast<const float4*>(src);
        ahi = *reinterpret_cast<const float4*>(src + 4);
    };
    auto writeA = [&](int buf) {  // 1 ds_write_b128
        bf16x8 v;
        v[0] = to_bf16(alo.x); v[1] = to_bf16(alo.y); v[2] = to_bf16(alo.z); v[3] = to_bf16(alo.w);
        v[4] = to_bf16(ahi.x); v[5] = to_bf16(ahi.y); v[6] = to_bf16(ahi.z); v[7] = to_bf16(ahi.w);
        *reinterpret_cast<bf16x8*>(ASB(buf) + a_dst) = v;
    };
    // B: 1536 chunks (3 planes x 128 rows x 4), 3 gloads/thread, src pre-swizzled
    auto stageB = [&](int buf, int kt) {
#pragma unroll
        for (int p = 0; p < 3; p++) {
            int cid = p * 512 + tid;
            int w = cid >> 9, rem = cid & 511;
            int row = rem >> 2, c = rem & 3;
            int cs = c ^ ((row >> 1) & 3);
            gload_lds16(Wt + (size_t)w * NDK * NDM + (size_t)row * NDM + kt * 32 + cs * 8,
                        BSB(buf) + (size_t)(p * 512 + wave * 64) * 8);
        }
    };

    f32x4 acc[3][4][2];
#pragma unroll
    for (int w = 0; w < 3; w++)
#pragma unroll
        for (int m = 0; m < 4; m++)
#pragma unroll
            for (int n = 0; n < 2; n++) acc[w][m][n] = (f32x4){0.f, 0.f, 0.f, 0.f};

    // ---- prologue ----
    loadA(0); SCHEDB(); stageB(0, 0); SCHEDB();   // flight: A0(2) B0(3)
    VMCNT(3);                                      // A0 done
    writeA(0);
    loadA(1); SCHEDB(); stageB(1, 1); SCHEDB();   // flight: B0(3) A1(2) B1(3)
    VMCNT(5);                                      // B0 done
    LGKM0();
    __builtin_amdgcn_s_barrier();                  // buf0 ready; B1 still flying

    for (int kt = 0; kt < 32; kt++) {
        const int cur = kt & 1;
        // ---- compute buf[cur]: 10 ds_read_b128 + 24 MFMA ----
        bf16x8 af[4];
#pragma unroll
        for (int m = 0; m < 4; m++) {
            int arow = wr * 64 + m * 16 + r16;
            int ch = kg ^ ((arow >> 1) & 3);
            af[m] = *reinterpret_cast<const bf16x8*>(ASB(cur) + (arow * 4 + ch) * 8);
        }
#pragma unroll
        for (int w = 0; w < 3; w++) {
#pragma unroll
            for (int n = 0; n < 2; n++) {
                int brow = wc * 32 + n * 16 + r16;
                int ch = kg ^ ((brow >> 1) & 3);
                bf16x8 bfw = *reinterpret_cast<const bf16x8*>(
                    BSB(cur) + ((w * 128 + brow) * 4 + ch) * 8);
#pragma unroll
                for (int m = 0; m < 4; m++)
                    acc[w][m][n] = __builtin_amdgcn_mfma_f32_16x16x32_bf16(af[m], bfw, acc[w][m][n], 0, 0, 0);
            }
        }

        if (kt + 1 < 32) {
            VMCNT(3);                          // A(t+1) regs landed (B(t+1) flying)
            writeA(1 - cur);
            LGKM0();                           // my ds_write visible
            __builtin_amdgcn_s_barrier();      // all waves done reading buf cur
            if (kt + 2 < 32) {
                loadA(kt + 2); SCHEDB(); stageB(cur, kt + 2); SCHEDB();
                VMCNT(5);                      // B(t+1) done; t+2 stage flying
            } else {
                VMCNT(0);                      // last buf: drain B(31)
            }
        }
    }

    // ---- epilogue ----
    __syncthreads();
    bf16 (*Tl)[136] = reinterpret_cast<bf16(*)[136]>(smem);
#pragma unroll
    for (int w = 0; w < 2; w++) {
        bf16* outw = qkv + (size_t)w * (size_t)(NB * NT) * NDK;
#pragma unroll
        for (int m = 0; m < 4; m++) {
            int rowb = mb * 128 + wr * 64 + m * 16 + kg * 4;
#pragma unroll
            for (int n = 0; n < 2; n++) {
                int col = wc * 32 + n * 16 + r16;
#pragma unroll
                for (int r = 0; r < 4; r++)
                    outw[(size_t)(rowb + r) * NDK + col] = to_bf16(acc[w][m][n][r]);
            }
        }
    }
#pragma unroll
    for (int m = 0; m < 4; m++) {
        int tl = wr * 64 + m * 16 + kg * 4;
#pragma unroll
        for (int n = 0; n < 2; n++) {
            int d = wc * 32 + n * 16 + r16;
            bf16x4 pv = { to_bf16(acc[2][m][n][0]), to_bf16(acc[2][m][n][1]),
                          to_bf16(acc[2][m][n][2]), to_bf16(acc[2][m][n][3]) };
            *reinterpret_cast<bf16x4*>(&Tl[d][tl]) = pv;
        }
    }
    __syncthreads();
    const int b = mb >> 4;
    const int t0 = (mb & 15) * 128;
    bf16* Vb = Vt + (size_t)b * NDK * NT;
#pragma unroll
    for (int p = 0; p < 4; p++) {
        int idx = p * 512 + tid;
        int d = idx >> 4, c = idx & 15;
        *reinterpret_cast<bf16x8*>(&Vb[(size_t)d * NT + t0 + c * 8]) =
            *reinterpret_cast<const bf16x8*>(&Tl[d][c * 8]);
    }
}

// ---------------------------------------------------------------------------
// Kernel 3: causal flash attention (unchanged: swapped-QK^T softmax, dbuf K/V
// LDS, 1 barrier/step, reg-prefetch, XCD-pinned batches).
// ---------------------------------------------------------------------------
__global__ __launch_bounds__(256) void attn_kernel(
        const bf16* __restrict__ Q, const bf16* __restrict__ K,
        const bf16* __restrict__ Vt, float* __restrict__ out) {
    __shared__ bf16 Ks[2][64][128];
    __shared__ bf16 Vs[2][128][64];
    __shared__ bf16 Ps[4][16][72];
    const int tid = threadIdx.x, lane = tid & 63, wave = tid >> 6;
    const int r16 = lane & 15, kg = lane >> 4;

    const int bid = blockIdx.x;
    const int xcd = bid & 7;
    const int j = bid >> 3;
    const int b = xcd * 2 + (j & 1);
    const int qb = (NT / 64 - 1) - (j >> 1);
    const int q0 = qb * 64;
    const size_t baseB = (size_t)b * NT * NDK;
    const size_t baseVt = (size_t)b * NDK * NT;

    const float scale = 0.08838834764831843f;
    bf16x8 qf[4];
    const int qglob = q0 + wave * 16 + r16;
#pragma unroll
    for (int kc = 0; kc < 4; kc++) {
        bf16x8 raw = *reinterpret_cast<const bf16x8*>(&Q[baseB + (size_t)qglob * NDK + kc * 32 + kg * 8]);
#pragma unroll
        for (int jj = 0; jj < 8; jj++) raw[jj] = to_bf16((float)raw[jj] * scale);
        qf[kc] = raw;
    }

    f32x4 o[8];
#pragma unroll
    for (int n = 0; n < 8; n++) o[n] = (f32x4){0.f, 0.f, 0.f, 0.f};
    float mrun = -INFINITY;
    float lrun = 0.f;

    int krow[4], kcol[4], vrow[4], vcol[4];
#pragma unroll
    for (int i = 0; i < 4; i++) {
        int idx = i * 256 + tid;
        krow[i] = idx >> 4; kcol[i] = idx & 15;
        vrow[i] = idx >> 3; vcol[i] = idx & 7;
    }

    const int nsteps = qb + 1;
    bf16x8 kreg[4], vreg[4];
#pragma unroll
    for (int i = 0; i < 4; i++) {
        kreg[i] = *reinterpret_cast<const bf16x8*>(&K[baseB + (size_t)krow[i] * NDK + kcol[i] * 8]);
        vreg[i] = *reinterpret_cast<const bf16x8*>(&Vt[baseVt + (size_t)vrow[i] * NT + vcol[i] * 8]);
    }
#pragma unroll
    for (int i = 0; i < 4; i++) {
        *reinterpret_cast<bf16x8*>(&Ks[0][krow[i]][(kcol[i] ^ (krow[i] & 7)) * 8]) = kreg[i];
        *reinterpret_cast<bf16x8*>(&Vs[0][vrow[i]][(vcol[i] ^ (vrow[i] & 7)) * 8]) = vreg[i];
    }
    if (nsteps > 1) {
#pragma unroll
        for (int i = 0; i < 4; i++) {
            kreg[i] = *reinterpret_cast<const bf16x8*>(&K[baseB + (size_t)(64 + krow[i]) * NDK + kcol[i] * 8]);
            vreg[i] = *reinterpret_cast<const bf16x8*>(&Vt[baseVt + (size_t)vrow[i] * NT + 64 + vcol[i] * 8]);
        }
    }
    __syncthreads();

    for (int s = 0; s < nsteps; s++) {
        const int cur = s & 1;
        const int kv0 = s * 64;

        f32x4 sfr[4];
#pragma unroll
        for (int n = 0; n < 4; n++) sfr[n] = (f32x4){0.f, 0.f, 0.f, 0.f};
#pragma unroll
        for (int n = 0; n < 4; n++) {
            const int krw = n * 16 + r16;
#pragma unroll
            for (int kc = 0; kc < 4; kc++) {
                bf16x8 kf = *reinterpret_cast<const bf16x8*>(&Ks[cur][krw][((kc * 4 + kg) ^ (krw & 7)) * 8]);
                sfr[n] = __builtin_amdgcn_mfma_f32_16x16x32_bf16(kf, qf[kc], sfr[n], 0, 0, 0);
            }
        }

        if (s == nsteps - 1) {
#pragma unroll
            for (int n = 0; n < 4; n++)
#pragma unroll
                for (int r = 0; r < 4; r++)
                    if (kv0 + n * 16 + kg * 4 + r > qglob) sfr[n][r] = -INFINITY;
        }

        float pm = -INFINITY;
#pragma unroll
        for (int n = 0; n < 4; n++) {
            float t0 = fmaxf(fmaxf(sfr[n][0], sfr[n][1]), fmaxf(sfr[n][2], sfr[n][3]));
            pm = fmaxf(pm, t0);
        }
        pm = fmaxf(pm, __shfl_xor(pm, 16, 64));
        pm = fmaxf(pm, __shfl_xor(pm, 32, 64));

        if (__any(pm > mrun)) {
            float mnew = fmaxf(mrun, pm);
            float corr = __expf(mrun - mnew);
            mrun = mnew;
            lrun *= corr;
            float co[4];
#pragma unroll
            for (int r = 0; r < 4; r++) co[r] = __shfl(corr, kg * 4 + r, 64);
#pragma unroll
            for (int n = 0; n < 8; n++)
#pragma unroll
                for (int r = 0; r < 4; r++) o[n][r] *= co[r];
        }

        float ps = 0.f;
#pragma unroll
        for (int n = 0; n < 4; n++) {
            bf16x4 pw;
#pragma unroll
            for (int r = 0; r < 4; r++) {
                float pv = __expf(sfr[n][r] - mrun);
                ps += pv;
                pw[r] = to_bf16(pv);
            }
            *reinterpret_cast<bf16x4*>(&Ps[wave][r16][n * 16 + kg * 4]) = pw;
        }
        ps += __shfl_xor(ps, 16, 64);
        ps += __shfl_xor(ps, 32, 64);
        lrun += ps;

#pragma unroll
        for (int kc2 = 0; kc2 < 2; kc2++) {
            bf16x8 pf = *reinterpret_cast<const bf16x8*>(&Ps[wave][r16][kc2 * 32 + kg * 8]);
#pragma unroll
            for (int n = 0; n < 8; n++) {
                const int vrw = n * 16 + r16;
                bf16x8 vf = *reinterpret_cast<const bf16x8*>(&Vs[cur][vrw][((kc2 * 4 + kg) ^ (vrw & 7)) * 8]);
                o[n] = __builtin_amdgcn_mfma_f32_16x16x32_bf16(pf, vf, o[n], 0, 0, 0);
            }
        }

        if (s + 1 < nsteps) {
#pragma unroll
            for (int i = 0; i < 4; i++) {
                *reinterpret_cast<bf16x8*>(&Ks[1 - cur][krow[i]][(kcol[i] ^ (krow[i] & 7)) * 8]) = kreg[i];
                *reinterpret_cast<bf16x8*>(&Vs[1 - cur][vrow[i]][(vcol[i] ^ (vrow[i] & 7)) * 8]) = vreg[i];
            }
            if (s + 2 < nsteps) {
                const int kv2 = (s + 2) * 64;
#pragma unroll
                for (int i = 0; i < 4; i++) {
                    kreg[i] = *reinterpret_cast<const bf16x8*>(&K[baseB + (size_t)(kv2 + krow[i]) * NDK + kcol[i] * 8]);
                    vreg[i] = *reinterpret_cast<const bf16x8*>(&Vt[baseVt + (size_t)vrow[i] * NT + kv2 + vcol[i] * 8]);
                }
            }
        }
        __syncthreads();
    }

    float linv = 1.0f / lrun;
    float li[4];
#pragma unroll
    for (int r = 0; r < 4; r++) li[r] = __shfl(linv, kg * 4 + r, 64);
#pragma unroll
    for (int n = 0; n < 8; n++)
#pragma unroll
        for (int r = 0; r < 4; r++) {
            int row = q0 + wave * 16 + kg * 4 + r;
            int col = n * 16 + r16;
            out[baseB + (size_t)row * NDK + col] = o[n][r] * li[r];
        }
}

// ---------------------------------------------------------------------------
extern "C" void kernel_launch(void* const* d_in, const int* in_sizes, int n_in,
                              void* d_out, int out_size, void* d_ws, size_t ws_size,
                              hipStream_t stream) {
    const float* x  = (const float*)d_in[0];
    const float* Wq = (const float*)d_in[1];
    const float* Wk = (const float*)d_in[2];
    const float* Wv = (const float*)d_in[3];
    float* out = (float*)d_out;

    char* ws = (char*)d_ws;
    bf16* Wt  = (bf16*)ws;                        // 768 KB
    bf16* qkv = (bf16*)(ws + (1ull << 20));       // Q,K planes: 16 MB
    bf16* Vtg = (bf16*)(ws + (26ull << 20));      // V^T [B][128][T]: 8 MB

    transpose_w_kernel<<<(3 * NDM * NDK) / 256, 256, 0, stream>>>(Wq, Wk, Wv, Wt);

    // fused QKV projection, counted-vmcnt pipeline (T4)
    proj_fused_kernel<<<(NB * NT) / 128, 512, 0, stream>>>(x, Wt, qkv, Vtg);

    bf16* Qp = qkv;
    bf16* Kp = qkv + (size_t)(NB * NT) * NDK;

    attn_kernel<<<dim3((NT / 64) * NB), 256, 0, stream>>>(Qp, Kp, Vtg, out);
}